// Round 6
// baseline (21654.294 us; speedup 1.0000x reference)
//
#include <hip/hip_runtime.h>
#include <hip/hip_bf16.h>
#include <math.h>

// ---------------------------------------------------------------------------
// GPoolBlock, round 6: de-scattered implicit-GEMM MFMA.
//  - weights pre-fragmented to MFMA lane order -> coalesced 1KB B-frag loads
//  - activations staged to LDS via global_load_lds (16B), 8KB tile shared by
//    8 waves, XOR-swizzled for conflict-free ds_read_b128, double-buffered
//  - conv1a+conv1b fused (N=256); conv2 operand-swapped (rows=co) fp32+resid
// Layouts: act channel-last zero-padded [b][441][C]; wfrag [cog][kc][lane][8].
// ---------------------------------------------------------------------------

#define BATCH   256
#define TRUNK_C 256
#define REG_C   192
#define GPOOL_C 64
#define HH      19
#define WW      19
#define HW      361
#define PP      441          // 21*21 padded pixels
#define EPS     1e-5f

typedef __hip_bfloat16 bf16;
typedef __attribute__((ext_vector_type(8))) short short8;
typedef __attribute__((ext_vector_type(4))) float floatx4;

__device__ __forceinline__ float b2f(bf16 v) { return __bfloat162float(v); }
__device__ __forceinline__ bf16  f2b(float v) { return __float2bfloat16(v); }

__device__ __forceinline__ float mish_f(float v) {
    float sp = (v > 20.0f) ? v : log1pf(expf(v));
    return v * tanhf(sp);
}

__device__ __forceinline__ void gload_lds16(const void* gsrc, void* lds) {
    __builtin_amdgcn_global_load_lds(
        (const __attribute__((address_space(1))) void*)gsrc,
        (__attribute__((address_space(3))) void*)lds, 16, 0, 0);
}

// --------------------------- prep: fold BN params ---------------------------
// bnbuf: [0:256] bn1_s [256:512] bn1_b [512:576] bn1b_s [576:640] bn1b_b
//        [640:832] bn2_s [832:1024] bn2_b
__global__ void prep_bn_kernel(const float* g1, const float* b1, const float* m1, const float* v1,
                               const float* g1b, const float* b1b, const float* m1b, const float* v1b,
                               const float* g2, const float* b2, const float* m2, const float* v2,
                               float* bnbuf) {
    int t = threadIdx.x;
    if (t < 256) {
        float s = g1[t] / sqrtf(v1[t] + EPS);
        bnbuf[t] = s;
        bnbuf[256 + t] = b1[t] - m1[t] * s;
    } else if (t < 320) {
        int c = t - 256;
        float s = g1b[c] / sqrtf(v1b[c] + EPS);
        bnbuf[512 + c] = s;
        bnbuf[576 + c] = b1b[c] - m1b[c] * s;
    } else if (t < 512) {
        int c = t - 320;
        float s = g2[c] / sqrtf(v2[c] + EPS);
        bnbuf[640 + c] = s;
        bnbuf[832 + c] = b2[c] - m2[c] * s;
    }
}

// ------------- prep: weights -> MFMA-fragment layout (bf16) -----------------
// w1c_p[((cog*72 + kc)*64 + lane)*8 + j]: co = cog*16 + (lane&15),
//   k = kc*32 + (lane>>4)*8 + j, r = k>>8, ci = k&255;
//   co<192 -> w1a, else w1b (combined 256-co matrix).
// w2_p analogous with K=1728 (kc 54), CIN=192.
__global__ void prep_w_kernel(const float* __restrict__ w1a, const float* __restrict__ w1b,
                              const float* __restrict__ w2,
                              bf16* __restrict__ w1c_p, bf16* __restrict__ w2_p) {
    const int T1 = 16 * 72 * 64 * 8;     // 589824
    const int T2 = 16 * 54 * 64 * 8;     // 442368
    for (int i = blockIdx.x * blockDim.x + threadIdx.x; i < T1 + T2;
         i += gridDim.x * blockDim.x) {
        if (i < T1) {
            int j = i & 7, lane = (i >> 3) & 63;
            int kc = (i >> 9) % 72, cog = (i >> 9) / 72;
            int co = cog * 16 + (lane & 15);
            int k = kc * 32 + ((lane >> 4) << 3) + j;
            int r = k >> 8, ci = k & 255;
            float v = (co < 192) ? w1a[co * 2304 + ci * 9 + r]
                                 : w1b[(co - 192) * 2304 + ci * 9 + r];
            w1c_p[i] = f2b(v);
        } else {
            int i2 = i - T1;
            int j = i2 & 7, lane = (i2 >> 3) & 63;
            int kc = (i2 >> 9) % 54, cog = (i2 >> 9) / 54;
            int co = cog * 16 + (lane & 15);
            int k = kc * 32 + ((lane >> 4) << 3) + j;
            int r = k / 192, ci = k % 192;
            w2_p[i2] = f2b(w2[co * 1728 + ci * 9 + r]);
        }
    }
}

// ---------------- zero the padded borders of act_pad and reg_pad ------------
__global__ void zero_border_kernel(bf16* __restrict__ act_pad, bf16* __restrict__ reg_pad) {
    int b = blockIdx.x;
    int t = threadIdx.x;     // 256
    for (int pp = 0; pp < PP; ++pp) {
        int r = pp / 21, c = pp % 21;
        bool border = (r == 0) | (r == 20) | (c == 0) | (c == 20);
        if (!border) continue;
        act_pad[((size_t)b * PP + pp) * TRUNK_C + t] = f2b(0.0f);
        if (t < REG_C) reg_pad[((size_t)b * PP + pp) * REG_C + t] = f2b(0.0f);
    }
}

// ------- bn1+mish + LDS transpose: x [b][256][361] fp32 -> act_pad CL bf16 --
__global__ __launch_bounds__(256)
void bn1_mish_t_kernel(const float* __restrict__ x, const float* __restrict__ bnbuf,
                       bf16* __restrict__ act_pad) {
    __shared__ float lds[256][32];    // XOR-swizzled columns
    int pc = blockIdx.x;              // pixel chunk of 32 (12 chunks)
    int b  = blockIdx.y;
    int t  = threadIdx.x;
    int p0 = pc * 32;
    int px = t & 31;
#pragma unroll
    for (int it = 0; it < 32; ++it) {          // 32 passes x 8 channels = 256
        int ci = it * 8 + (t >> 5);
        int p  = p0 + px;
        float v = 0.0f;
        if (p < HW) v = x[((size_t)b * TRUNK_C + ci) * HW + p];
        v = v * bnbuf[ci] + bnbuf[256 + ci];
        lds[ci][px ^ (ci >> 3)] = mish_f(v);
    }
    __syncthreads();
#pragma unroll
    for (int it = 0; it < 4; ++it) {
        int pl = it * 8 + (t >> 5);
        int p  = p0 + pl;
        if (p >= HW) continue;
        int ch = t & 31;                       // channel block: ch*8 .. ch*8+7
        short8 vv;
#pragma unroll
        for (int j = 0; j < 8; ++j) {
            bf16 h = f2b(lds[ch * 8 + j][pl ^ ch]);
            short s;
            __builtin_memcpy(&s, &h, 2);
            vv[j] = s;
        }
        int pp = (p / WW + 1) * 21 + (p % WW + 1);
        *(short8*)(act_pad + ((size_t)b * PP + pp) * TRUNK_C + ch * 8) = vv;
    }
}

// ---------------------- conv1 fused (act x W -> 256 co) ---------------------
// Block: 512 thr (8 waves, mi 0..1 x ni 0..3). Tile M=128 px, N=256 co, BK=32.
// A-tile (128px x 32ci, 8KB) double-buffered in LDS via global_load_lds,
// XOR-swizzled. B-frags: coalesced 1KB loads from fragmented weights.
// co<192 -> reg_pad raw (padded CL); co>=192 -> gp (bn1b+mish, CL).
__global__ __launch_bounds__(512)
void conv1_kernel(const bf16* __restrict__ act,     // [b][441][256]
                  const bf16* __restrict__ wfrag,   // [16][72][64][8]
                  bf16* __restrict__ reg_out,       // [b][441][192]
                  bf16* __restrict__ gp_out,        // [b][361][64]
                  const float* __restrict__ ep_scale, const float* __restrict__ ep_bias) {
    const int CIN = 256, NKC = 72;
    __shared__ __align__(16) bf16 atile[2][128 * 32];
    const int b   = blockIdx.x;
    const int mt  = blockIdx.y;
    const int t   = threadIdx.x;
    const int w   = t >> 6, lane = t & 63;
    const int mi  = w >> 2, ni = w & 3;
    const int l15 = lane & 15, quad = lane >> 4;

    // staging source: thread t loads 16B of pixel row (t>>2), sub-chunk swizzled
    int spxl = t >> 2;                       // 0..127 LDS row
    int sq   = t & 3;
    int ss   = sq ^ ((spxl >> 1) & 3);       // swizzled ci sub-chunk
    int sp   = mt * 128 + spxl; if (sp > 360) sp = 360;
    const bf16* sbase = act + ((size_t)b * PP + (sp / WW) * 21 + (sp % WW)) * CIN + (ss << 3);

    // B-frag bases (fragmented weights): cog = ni*4+ns
    const bf16* wb[4];
#pragma unroll
    for (int ns = 0; ns < 4; ++ns)
        wb[ns] = wfrag + ((size_t)(ni * 4 + ns) * NKC * 64 + lane) * 8;

    // A-frag LDS element offsets (within one buffer)
    int aoff[4];
#pragma unroll
    for (int ms = 0; ms < 4; ++ms) {
        int row = mi * 64 + ms * 16 + l15;
        aoff[ms] = row * 32 + ((quad ^ ((row >> 1) & 3)) << 3);
    }

    auto stage = [&](int buf, int kc) {
        int r = kc >> 3, c = kc & 7;
        int off = ((r / 3) * 21 + (r % 3)) * CIN + (c << 5);
        gload_lds16(sbase + off, atile[buf] + (w << 9));
    };

    floatx4 acc[4][4];
#pragma unroll
    for (int i = 0; i < 4; ++i)
#pragma unroll
        for (int j = 0; j < 4; ++j) acc[i][j] = (floatx4){0.f, 0.f, 0.f, 0.f};

    short8 bfr[2][4], afr[4];
    stage(0, 0);
#pragma unroll
    for (int ns = 0; ns < 4; ++ns) bfr[0][ns] = *(const short8*)(wb[ns]);

    for (int kc = 0; kc < NKC; ++kc) {
        int cur = kc & 1;
        __syncthreads();                       // atile[cur] + bfr[cur] ready
        if (kc + 1 < NKC) stage(cur ^ 1, kc + 1);
#pragma unroll
        for (int ms = 0; ms < 4; ++ms)
            afr[ms] = *(const short8*)(atile[cur] + aoff[ms]);
        if (kc + 1 < NKC) {
#pragma unroll
            for (int ns = 0; ns < 4; ++ns)
                bfr[cur ^ 1][ns] = *(const short8*)(wb[ns] + (size_t)(kc + 1) * 512);
        }
#pragma unroll
        for (int ms = 0; ms < 4; ++ms)
#pragma unroll
            for (int ns = 0; ns < 4; ++ns)
                acc[ms][ns] = __builtin_amdgcn_mfma_f32_16x16x32_bf16(
                    afr[ms], bfr[cur][ns], acc[ms][ns], 0, 0, 0);
    }

    // epilogue: D rows = px (quad*4+rg), cols = co (l15)
    float scl[4], bia[4];
#pragma unroll
    for (int ns = 0; ns < 4; ++ns) {
        int co = (ni * 4 + ns) * 16 + l15;
        if (co >= 192) { scl[ns] = ep_scale[co - 192]; bia[ns] = ep_bias[co - 192]; }
    }
#pragma unroll
    for (int ms = 0; ms < 4; ++ms) {
#pragma unroll
        for (int rg = 0; rg < 4; ++rg) {
            int p = mt * 128 + mi * 64 + ms * 16 + quad * 4 + rg;
            if (p > 360) continue;
            size_t ppad = (size_t)b * PP + (p / WW + 1) * 21 + (p % WW + 1);
#pragma unroll
            for (int ns = 0; ns < 4; ++ns) {
                int co = (ni * 4 + ns) * 16 + l15;
                float v = acc[ms][ns][rg];
                if (co < 192) {
                    reg_out[ppad * REG_C + co] = f2b(v);
                } else {
                    v = mish_f(v * scl[ns] + bia[ns]);
                    gp_out[((size_t)b * HW + p) * GPOOL_C + (co - 192)] = f2b(v);
                }
            }
        }
    }
}

// ------------------- conv2 (W x act -> channel-first fp32) ------------------
// Block: 512 thr (8 waves, pw 0..1 x cw 0..3). Tile 256 co x 128 px, BK=32.
// A = fragmented weights (rows=co), B = act frags from LDS tile. +resid.
__global__ __launch_bounds__(512)
void conv2_kernel(const bf16* __restrict__ act,     // reg_pad [b][441][192]
                  const bf16* __restrict__ wfrag,   // [16][54][64][8]
                  const float* __restrict__ resid,
                  float* __restrict__ out) {
    const int CIN = 192, NKC = 54;
    __shared__ __align__(16) bf16 atile[2][128 * 32];
    const int b   = blockIdx.x;
    const int mt  = blockIdx.y;
    const int t   = threadIdx.x;
    const int w   = t >> 6, lane = t & 63;
    const int pw  = w >> 2, cw = w & 3;
    const int l15 = lane & 15, quad = lane >> 4;

    int spxl = t >> 2;
    int sq   = t & 3;
    int ss   = sq ^ ((spxl >> 1) & 3);
    int sp   = mt * 128 + spxl; if (sp > 360) sp = 360;
    const bf16* sbase = act + ((size_t)b * PP + (sp / WW) * 21 + (sp % WW)) * CIN + (ss << 3);

    const bf16* wb[4];
#pragma unroll
    for (int ms = 0; ms < 4; ++ms)
        wb[ms] = wfrag + ((size_t)(cw * 4 + ms) * NKC * 64 + lane) * 8;

    int aoff[4];
#pragma unroll
    for (int ns = 0; ns < 4; ++ns) {
        int row = pw * 64 + ns * 16 + l15;
        aoff[ns] = row * 32 + ((quad ^ ((row >> 1) & 3)) << 3);
    }

    auto stage = [&](int buf, int kc) {
        int r = kc / 6, c = kc % 6;
        int off = ((r / 3) * 21 + (r % 3)) * CIN + (c << 5);
        gload_lds16(sbase + off, atile[buf] + (w << 9));
    };

    floatx4 acc[4][4];
#pragma unroll
    for (int i = 0; i < 4; ++i)
#pragma unroll
        for (int j = 0; j < 4; ++j) acc[i][j] = (floatx4){0.f, 0.f, 0.f, 0.f};

    short8 wfr[2][4], bfa[4];
    stage(0, 0);
#pragma unroll
    for (int ms = 0; ms < 4; ++ms) wfr[0][ms] = *(const short8*)(wb[ms]);

    for (int kc = 0; kc < NKC; ++kc) {
        int cur = kc & 1;
        __syncthreads();
        if (kc + 1 < NKC) stage(cur ^ 1, kc + 1);
#pragma unroll
        for (int ns = 0; ns < 4; ++ns)
            bfa[ns] = *(const short8*)(atile[cur] + aoff[ns]);
        if (kc + 1 < NKC) {
#pragma unroll
            for (int ms = 0; ms < 4; ++ms)
                wfr[cur ^ 1][ms] = *(const short8*)(wb[ms] + (size_t)(kc + 1) * 512);
        }
#pragma unroll
        for (int ms = 0; ms < 4; ++ms)
#pragma unroll
            for (int ns = 0; ns < 4; ++ns)
                acc[ms][ns] = __builtin_amdgcn_mfma_f32_16x16x32_bf16(
                    wfr[cur][ms], bfa[ns], acc[ms][ns], 0, 0, 0);
    }

    // epilogue: D rows = co (quad*4+rg), cols = px (l15)
#pragma unroll
    for (int ns = 0; ns < 4; ++ns) {
        int p = mt * 128 + pw * 64 + ns * 16 + l15;
        if (p > 360) continue;
#pragma unroll
        for (int ms = 0; ms < 4; ++ms) {
#pragma unroll
            for (int rg = 0; rg < 4; ++rg) {
                int co = (cw * 4 + ms) * 16 + quad * 4 + rg;
                size_t idx = ((size_t)b * TRUNK_C + co) * HW + p;
                out[idx] = acc[ms][ns][rg] + resid[idx];
            }
        }
    }
}

// ------------------------------ kata gpool ----------------------------------
__global__ void gpool_kernel(const bf16* __restrict__ gp, float* __restrict__ pooled) {
    __shared__ float ls[4][64], lm[4][64];
    int b = blockIdx.x;
    int t = threadIdx.x;          // 256
    int c = t & 63, sub = t >> 6;
    float s = 0.0f, mx = -1e30f;
    for (int p = sub; p < HW; p += 4) {
        float v = b2f(gp[((size_t)b * HW + p) * GPOOL_C + c]);
        s += v;
        mx = fmaxf(mx, v);
    }
    ls[sub][c] = s; lm[sub][c] = mx;
    __syncthreads();
    if (t < 64) {
        float ss = ls[0][t] + ls[1][t] + ls[2][t] + ls[3][t];
        float mm = fmaxf(fmaxf(lm[0][t], lm[1][t]), fmaxf(lm[2][t], lm[3][t]));
        float mean = ss * (1.0f / 361.0f);
        pooled[b * 192 + t] = mean;
        pooled[b * 192 + 64 + t] = mean * 0.5f;
        pooled[b * 192 + 128 + t] = mm;
    }
}

// -------------------------- tiny linear (192x192) ---------------------------
__global__ void lin_kernel(const float* __restrict__ pooled, const float* __restrict__ w_lin,
                           float* __restrict__ gpout) {
    int i = blockIdx.x * blockDim.x + threadIdx.x;
    if (i >= BATCH * REG_C) return;
    int b = i / REG_C;
    int oc = i - b * REG_C;
    const float* pr = pooled + b * 192;
    const float* wr = w_lin + oc * 192;
    float s = 0.0f;
    for (int j = 0; j < 192; ++j) s = fmaf(pr[j], wr[j], s);
    gpout[i] = s;
}

// ------------- add gpool bias + bn2 + mish, in-place on reg_pad -------------
__global__ void add_bn2_mish_kernel(bf16* __restrict__ reg_pad, const float* __restrict__ gpout,
                                    const float* __restrict__ bnbuf) {
    const int n = BATCH * HW * REG_C;
    int i = blockIdx.x * blockDim.x + threadIdx.x;
    if (i >= n) return;
    int c = i % REG_C;
    int bp = i / REG_C;
    int p = bp % HW;
    int b = bp / HW;
    int pp = (p / WW + 1) * 21 + (p % WW + 1);
    size_t idx = ((size_t)b * PP + pp) * REG_C + c;
    float v = b2f(reg_pad[idx]) + gpout[b * 192 + c];
    v = v * bnbuf[640 + c] + bnbuf[832 + c];
    reg_pad[idx] = f2b(mish_f(v));
}

// ---------------------------------------------------------------------------
extern "C" void kernel_launch(void* const* d_in, const int* in_sizes, int n_in,
                              void* d_out, int out_size, void* d_ws, size_t ws_size,
                              hipStream_t stream) {
    const float* x     = (const float*)d_in[0];
    const float* bn1_g = (const float*)d_in[1];
    const float* bn1_b = (const float*)d_in[2];
    const float* bn1_m = (const float*)d_in[3];
    const float* bn1_v = (const float*)d_in[4];
    const float* w1a   = (const float*)d_in[5];
    const float* w1b   = (const float*)d_in[6];
    const float* bn1b_g = (const float*)d_in[7];
    const float* bn1b_b = (const float*)d_in[8];
    const float* bn1b_m = (const float*)d_in[9];
    const float* bn1b_v = (const float*)d_in[10];
    const float* w_lin  = (const float*)d_in[11];
    const float* bn2_g  = (const float*)d_in[12];
    const float* bn2_b  = (const float*)d_in[13];
    const float* bn2_m  = (const float*)d_in[14];
    const float* bn2_v  = (const float*)d_in[15];
    const float* w2     = (const float*)d_in[16];
    float* out = (float*)d_out;

    char* ws = (char*)d_ws;
    size_t off = 0;
    auto alloc = [&](size_t bytes) {
        void* p = ws + off;
        off += (bytes + 255) & ~(size_t)255;
        return p;
    };
    bf16*  act_pad = (bf16*)alloc((size_t)BATCH * PP * TRUNK_C * sizeof(bf16));
    bf16*  reg_pad = (bf16*)alloc((size_t)BATCH * PP * REG_C * sizeof(bf16));
    bf16*  gp      = (bf16*)alloc((size_t)BATCH * HW * GPOOL_C * sizeof(bf16));
    bf16*  w1c_p   = (bf16*)alloc((size_t)16 * 72 * 64 * 8 * sizeof(bf16));
    bf16*  w2_p    = (bf16*)alloc((size_t)16 * 54 * 64 * 8 * sizeof(bf16));
    float* pooled  = (float*)alloc((size_t)BATCH * 192 * sizeof(float));
    float* gpout   = (float*)alloc((size_t)BATCH * 192 * sizeof(float));
    float* bnbuf   = (float*)alloc(1024 * sizeof(float));
    (void)ws_size;

    // 1. prep
    hipLaunchKernelGGL(prep_bn_kernel, dim3(1), dim3(512), 0, stream,
                       bn1_g, bn1_b, bn1_m, bn1_v,
                       bn1b_g, bn1b_b, bn1b_m, bn1b_v,
                       bn2_g, bn2_b, bn2_m, bn2_v, bnbuf);
    hipLaunchKernelGGL(prep_w_kernel, dim3(1024), dim3(256), 0, stream,
                       w1a, w1b, w2, w1c_p, w2_p);
    hipLaunchKernelGGL(zero_border_kernel, dim3(BATCH), dim3(256), 0, stream,
                       act_pad, reg_pad);

    // 2. act_pad = mish(bn1(x)), LDS-tiled transpose to channel-last padded
    hipLaunchKernelGGL(bn1_mish_t_kernel, dim3(12, BATCH), dim3(256), 0, stream,
                       x, bnbuf, act_pad);

    // 3. fused conv1: reg_pad raw interior + gp = mish(bn1b(conv))
    hipLaunchKernelGGL(conv1_kernel, dim3(BATCH, 3), dim3(512), 0, stream,
                       act_pad, w1c_p, reg_pad, gp, bnbuf + 512, bnbuf + 576);

    // 4. pooled = kata_gpool(gp); gpout = pooled @ w_lin^T
    hipLaunchKernelGGL(gpool_kernel, dim3(BATCH), dim3(256), 0, stream, gp, pooled);
    hipLaunchKernelGGL(lin_kernel, dim3((BATCH * REG_C + 255) / 256), dim3(256), 0, stream,
                       pooled, w_lin, gpout);

    // 5. reg_pad = mish(bn2(reg_pad + gpout)) in-place (interior only)
    {
        int n = BATCH * HW * REG_C;
        hipLaunchKernelGGL(add_bn2_mish_kernel, dim3((n + 255) / 256), dim3(256), 0, stream,
                           reg_pad, gpout, bnbuf);
    }

    // 6. out = conv(reg_pad, w2) + x, channel-first fp32
    hipLaunchKernelGGL(conv2_kernel, dim3(BATCH, 3), dim3(512), 0, stream,
                       reg_pad, w2_p, x, out);
}

// Round 7
// 760.698 us; speedup vs baseline: 28.4663x; 28.4663x over previous
//
#include <hip/hip_runtime.h>
#include <hip/hip_bf16.h>
#include <math.h>

// ---------------------------------------------------------------------------
// GPoolBlock, round 7: de-scattered implicit-GEMM MFMA, spill-free pipeline.
//  - weights pre-fragmented to MFMA lane order -> coalesced 1KB B-frag loads
//  - activations staged to LDS via global_load_lds (16B), 8KB tile shared by
//    8 waves, XOR-swizzled for conflict-free ds_read_b128, double-buffered
//  - K-loop manually unrolled x2: ALL register arrays compile-time indexed
//    (round 6's bfr[cur][ns] runtime index demoted frags to scratch -> 200x)
// Layouts: act channel-last zero-padded [b][441][C]; wfrag [cog][kc][lane][8].
// ---------------------------------------------------------------------------

#define BATCH   256
#define TRUNK_C 256
#define REG_C   192
#define GPOOL_C 64
#define HH      19
#define WW      19
#define HW      361
#define PP      441          // 21*21 padded pixels
#define EPS     1e-5f

typedef __hip_bfloat16 bf16;
typedef __attribute__((ext_vector_type(8))) short short8;
typedef __attribute__((ext_vector_type(4))) float floatx4;

__device__ __forceinline__ float b2f(bf16 v) { return __bfloat162float(v); }
__device__ __forceinline__ bf16  f2b(float v) { return __float2bfloat16(v); }

__device__ __forceinline__ float mish_f(float v) {
    float sp = (v > 20.0f) ? v : log1pf(expf(v));
    return v * tanhf(sp);
}

__device__ __forceinline__ void gload_lds16(const void* gsrc, void* lds) {
    __builtin_amdgcn_global_load_lds(
        (const __attribute__((address_space(1))) void*)gsrc,
        (__attribute__((address_space(3))) void*)lds, 16, 0, 0);
}

// --------------------------- prep: fold BN params ---------------------------
// bnbuf: [0:256] bn1_s [256:512] bn1_b [512:576] bn1b_s [576:640] bn1b_b
//        [640:832] bn2_s [832:1024] bn2_b
__global__ void prep_bn_kernel(const float* g1, const float* b1, const float* m1, const float* v1,
                               const float* g1b, const float* b1b, const float* m1b, const float* v1b,
                               const float* g2, const float* b2, const float* m2, const float* v2,
                               float* bnbuf) {
    int t = threadIdx.x;
    if (t < 256) {
        float s = g1[t] / sqrtf(v1[t] + EPS);
        bnbuf[t] = s;
        bnbuf[256 + t] = b1[t] - m1[t] * s;
    } else if (t < 320) {
        int c = t - 256;
        float s = g1b[c] / sqrtf(v1b[c] + EPS);
        bnbuf[512 + c] = s;
        bnbuf[576 + c] = b1b[c] - m1b[c] * s;
    } else if (t < 512) {
        int c = t - 320;
        float s = g2[c] / sqrtf(v2[c] + EPS);
        bnbuf[640 + c] = s;
        bnbuf[832 + c] = b2[c] - m2[c] * s;
    }
}

// ------------- prep: weights -> MFMA-fragment layout (bf16) -----------------
// w1c_p[((cog*72 + kc)*64 + lane)*8 + j]: co = cog*16 + (lane&15),
//   k = kc*32 + (lane>>4)*8 + j, r = k>>8, ci = k&255;
//   co<192 -> w1a, else w1b (combined 256-co matrix).
// w2_p analogous with K=1728 (kc 54), CIN=192.
__global__ void prep_w_kernel(const float* __restrict__ w1a, const float* __restrict__ w1b,
                              const float* __restrict__ w2,
                              bf16* __restrict__ w1c_p, bf16* __restrict__ w2_p) {
    const int T1 = 16 * 72 * 64 * 8;     // 589824
    const int T2 = 16 * 54 * 64 * 8;     // 442368
    for (int i = blockIdx.x * blockDim.x + threadIdx.x; i < T1 + T2;
         i += gridDim.x * blockDim.x) {
        if (i < T1) {
            int j = i & 7, lane = (i >> 3) & 63;
            int kc = (i >> 9) % 72, cog = (i >> 9) / 72;
            int co = cog * 16 + (lane & 15);
            int k = kc * 32 + ((lane >> 4) << 3) + j;
            int r = k >> 8, ci = k & 255;
            float v = (co < 192) ? w1a[co * 2304 + ci * 9 + r]
                                 : w1b[(co - 192) * 2304 + ci * 9 + r];
            w1c_p[i] = f2b(v);
        } else {
            int i2 = i - T1;
            int j = i2 & 7, lane = (i2 >> 3) & 63;
            int kc = (i2 >> 9) % 54, cog = (i2 >> 9) / 54;
            int co = cog * 16 + (lane & 15);
            int k = kc * 32 + ((lane >> 4) << 3) + j;
            int r = k / 192, ci = k % 192;
            w2_p[i2] = f2b(w2[co * 1728 + ci * 9 + r]);
        }
    }
}

// ---------------- zero the padded borders of act_pad and reg_pad ------------
__global__ void zero_border_kernel(bf16* __restrict__ act_pad, bf16* __restrict__ reg_pad) {
    int b = blockIdx.x;
    int t = threadIdx.x;     // 256
    for (int pp = 0; pp < PP; ++pp) {
        int r = pp / 21, c = pp % 21;
        bool border = (r == 0) | (r == 20) | (c == 0) | (c == 20);
        if (!border) continue;
        act_pad[((size_t)b * PP + pp) * TRUNK_C + t] = f2b(0.0f);
        if (t < REG_C) reg_pad[((size_t)b * PP + pp) * REG_C + t] = f2b(0.0f);
    }
}

// ------- bn1+mish + LDS transpose: x [b][256][361] fp32 -> act_pad CL bf16 --
__global__ __launch_bounds__(256)
void bn1_mish_t_kernel(const float* __restrict__ x, const float* __restrict__ bnbuf,
                       bf16* __restrict__ act_pad) {
    __shared__ float lds[256][32];    // XOR-swizzled columns
    int pc = blockIdx.x;              // pixel chunk of 32 (12 chunks)
    int b  = blockIdx.y;
    int t  = threadIdx.x;
    int p0 = pc * 32;
    int px = t & 31;
#pragma unroll
    for (int it = 0; it < 32; ++it) {          // 32 passes x 8 channels = 256
        int ci = it * 8 + (t >> 5);
        int p  = p0 + px;
        float v = 0.0f;
        if (p < HW) v = x[((size_t)b * TRUNK_C + ci) * HW + p];
        v = v * bnbuf[ci] + bnbuf[256 + ci];
        lds[ci][px ^ (ci >> 3)] = mish_f(v);
    }
    __syncthreads();
#pragma unroll
    for (int it = 0; it < 4; ++it) {
        int pl = it * 8 + (t >> 5);
        int p  = p0 + pl;
        if (p >= HW) continue;
        int ch = t & 31;                       // channel block: ch*8 .. ch*8+7
        short8 vv;
#pragma unroll
        for (int j = 0; j < 8; ++j) {
            bf16 h = f2b(lds[ch * 8 + j][pl ^ ch]);
            short s;
            __builtin_memcpy(&s, &h, 2);
            vv[j] = s;
        }
        int pp = (p / WW + 1) * 21 + (p % WW + 1);
        *(short8*)(act_pad + ((size_t)b * PP + pp) * TRUNK_C + ch * 8) = vv;
    }
}

// ---------------------- conv1 fused (act x W -> 256 co) ---------------------
// Block: 512 thr (8 waves, mi 0..1 x ni 0..3). Tile M=128 px, N=256 co, BK=32.
// A-tile (128px x 32ci, 8KB) double-buffered in LDS via global_load_lds,
// XOR-swizzled. B-frags: coalesced 1KB loads from fragmented weights.
// co<192 -> reg_pad raw (padded CL); co>=192 -> gp (bn1b+mish, CL).
__global__ __launch_bounds__(512)
void conv1_kernel(const bf16* __restrict__ act,     // [b][441][256]
                  const bf16* __restrict__ wfrag,   // [16][72][64][8]
                  bf16* __restrict__ reg_out,       // [b][441][192]
                  bf16* __restrict__ gp_out,        // [b][361][64]
                  const float* __restrict__ ep_scale, const float* __restrict__ ep_bias) {
    const int CIN = 256, NKC = 72;
    __shared__ __align__(16) bf16 atile0[128 * 32];
    __shared__ __align__(16) bf16 atile1[128 * 32];
    const int b   = blockIdx.x;
    const int mt  = blockIdx.y;
    const int t   = threadIdx.x;
    const int w   = t >> 6, lane = t & 63;
    const int mi  = w >> 2, ni = w & 3;
    const int l15 = lane & 15, quad = lane >> 4;

    // staging source: thread t loads 16B of pixel row (t>>2), sub-chunk swizzled
    int spxl = t >> 2;                       // 0..127 LDS row
    int sq   = t & 3;
    int ss   = sq ^ ((spxl >> 1) & 3);       // swizzled ci sub-chunk
    int sp   = mt * 128 + spxl; if (sp > 360) sp = 360;
    const bf16* sbase = act + ((size_t)b * PP + (sp / WW) * 21 + (sp % WW)) * CIN + (ss << 3);

    // B-frag bases (fragmented weights): cog = ni*4+ns
    const bf16* wb[4];
#pragma unroll
    for (int ns = 0; ns < 4; ++ns)
        wb[ns] = wfrag + ((size_t)(ni * 4 + ns) * NKC * 64 + lane) * 8;

    // A-frag LDS element offsets (within one buffer)
    int aoff[4];
#pragma unroll
    for (int ms = 0; ms < 4; ++ms) {
        int row = mi * 64 + ms * 16 + l15;
        aoff[ms] = row * 32 + ((quad ^ ((row >> 1) & 3)) << 3);
    }

    auto stage = [&](bf16* tilebuf, int kc) {
        int r = kc >> 3, c = kc & 7;
        int off = ((r / 3) * 21 + (r % 3)) * CIN + (c << 5);
        gload_lds16(sbase + off, tilebuf + (w << 9));
    };

    floatx4 acc[4][4];
#pragma unroll
    for (int i = 0; i < 4; ++i)
#pragma unroll
        for (int j = 0; j < 4; ++j) acc[i][j] = (floatx4){0.f, 0.f, 0.f, 0.f};

    short8 afr[4], bfrA[4], bfrB[4];
    stage(atile0, 0);
#pragma unroll
    for (int ns = 0; ns < 4; ++ns) bfrA[ns] = *(const short8*)(wb[ns]);

    for (int kc = 0; kc < NKC; kc += 2) {
        // ---- even chunk: buffer 0, frags bfrA ----
        __syncthreads();                       // atile0 staged
        if (kc + 1 < NKC) {
            stage(atile1, kc + 1);
#pragma unroll
            for (int ns = 0; ns < 4; ++ns)
                bfrB[ns] = *(const short8*)(wb[ns] + (size_t)(kc + 1) * 512);
        }
#pragma unroll
        for (int ms = 0; ms < 4; ++ms)
            afr[ms] = *(const short8*)(atile0 + aoff[ms]);
#pragma unroll
        for (int ms = 0; ms < 4; ++ms)
#pragma unroll
            for (int ns = 0; ns < 4; ++ns)
                acc[ms][ns] = __builtin_amdgcn_mfma_f32_16x16x32_bf16(
                    afr[ms], bfrA[ns], acc[ms][ns], 0, 0, 0);

        // ---- odd chunk: buffer 1, frags bfrB ----
        __syncthreads();                       // atile1 staged
        if (kc + 2 < NKC) {
            stage(atile0, kc + 2);
#pragma unroll
            for (int ns = 0; ns < 4; ++ns)
                bfrA[ns] = *(const short8*)(wb[ns] + (size_t)(kc + 2) * 512);
        }
#pragma unroll
        for (int ms = 0; ms < 4; ++ms)
            afr[ms] = *(const short8*)(atile1 + aoff[ms]);
#pragma unroll
        for (int ms = 0; ms < 4; ++ms)
#pragma unroll
            for (int ns = 0; ns < 4; ++ns)
                acc[ms][ns] = __builtin_amdgcn_mfma_f32_16x16x32_bf16(
                    afr[ms], bfrB[ns], acc[ms][ns], 0, 0, 0);
    }

    // epilogue: D rows = px (quad*4+rg), cols = co (l15)
    float scl[4], bia[4];
#pragma unroll
    for (int ns = 0; ns < 4; ++ns) {
        int co = (ni * 4 + ns) * 16 + l15;
        if (co >= 192) { scl[ns] = ep_scale[co - 192]; bia[ns] = ep_bias[co - 192]; }
    }
#pragma unroll
    for (int ms = 0; ms < 4; ++ms) {
#pragma unroll
        for (int rg = 0; rg < 4; ++rg) {
            int p = mt * 128 + mi * 64 + ms * 16 + quad * 4 + rg;
            if (p > 360) continue;
            size_t ppad = (size_t)b * PP + (p / WW + 1) * 21 + (p % WW + 1);
#pragma unroll
            for (int ns = 0; ns < 4; ++ns) {
                int co = (ni * 4 + ns) * 16 + l15;
                float v = acc[ms][ns][rg];
                if (co < 192) {
                    reg_out[ppad * REG_C + co] = f2b(v);
                } else {
                    v = mish_f(v * scl[ns] + bia[ns]);
                    gp_out[((size_t)b * HW + p) * GPOOL_C + (co - 192)] = f2b(v);
                }
            }
        }
    }
}

// ------------------- conv2 (W x act -> channel-first fp32) ------------------
// Block: 512 thr (8 waves, pw 0..1 x cw 0..3). Tile 256 co x 128 px, BK=32.
// A = fragmented weights (rows=co), B = act frags from LDS tile. +resid.
__global__ __launch_bounds__(512)
void conv2_kernel(const bf16* __restrict__ act,     // reg_pad [b][441][192]
                  const bf16* __restrict__ wfrag,   // [16][54][64][8]
                  const float* __restrict__ resid,
                  float* __restrict__ out) {
    const int CIN = 192, NKC = 54;
    __shared__ __align__(16) bf16 atile0[128 * 32];
    __shared__ __align__(16) bf16 atile1[128 * 32];
    const int b   = blockIdx.x;
    const int mt  = blockIdx.y;
    const int t   = threadIdx.x;
    const int w   = t >> 6, lane = t & 63;
    const int pw  = w >> 2, cw = w & 3;
    const int l15 = lane & 15, quad = lane >> 4;

    int spxl = t >> 2;
    int sq   = t & 3;
    int ss   = sq ^ ((spxl >> 1) & 3);
    int sp   = mt * 128 + spxl; if (sp > 360) sp = 360;
    const bf16* sbase = act + ((size_t)b * PP + (sp / WW) * 21 + (sp % WW)) * CIN + (ss << 3);

    const bf16* wb[4];
#pragma unroll
    for (int ms = 0; ms < 4; ++ms)
        wb[ms] = wfrag + ((size_t)(cw * 4 + ms) * NKC * 64 + lane) * 8;

    int aoff[4];
#pragma unroll
    for (int ns = 0; ns < 4; ++ns) {
        int row = pw * 64 + ns * 16 + l15;
        aoff[ns] = row * 32 + ((quad ^ ((row >> 1) & 3)) << 3);
    }

    auto stage = [&](bf16* tilebuf, int kc) {
        int r = kc / 6, c = kc % 6;
        int off = ((r / 3) * 21 + (r % 3)) * CIN + (c << 5);
        gload_lds16(sbase + off, tilebuf + (w << 9));
    };

    floatx4 acc[4][4];
#pragma unroll
    for (int i = 0; i < 4; ++i)
#pragma unroll
        for (int j = 0; j < 4; ++j) acc[i][j] = (floatx4){0.f, 0.f, 0.f, 0.f};

    short8 bfa[4], wfrA[4], wfrB[4];
    stage(atile0, 0);
#pragma unroll
    for (int ms = 0; ms < 4; ++ms) wfrA[ms] = *(const short8*)(wb[ms]);

    for (int kc = 0; kc < NKC; kc += 2) {
        // ---- even chunk: buffer 0, frags wfrA ----
        __syncthreads();
        if (kc + 1 < NKC) {
            stage(atile1, kc + 1);
#pragma unroll
            for (int ms = 0; ms < 4; ++ms)
                wfrB[ms] = *(const short8*)(wb[ms] + (size_t)(kc + 1) * 512);
        }
#pragma unroll
        for (int ns = 0; ns < 4; ++ns)
            bfa[ns] = *(const short8*)(atile0 + aoff[ns]);
#pragma unroll
        for (int ms = 0; ms < 4; ++ms)
#pragma unroll
            for (int ns = 0; ns < 4; ++ns)
                acc[ms][ns] = __builtin_amdgcn_mfma_f32_16x16x32_bf16(
                    wfrA[ms], bfa[ns], acc[ms][ns], 0, 0, 0);

        // ---- odd chunk: buffer 1, frags wfrB ----
        __syncthreads();
        if (kc + 2 < NKC) {
            stage(atile0, kc + 2);
#pragma unroll
            for (int ms = 0; ms < 4; ++ms)
                wfrA[ms] = *(const short8*)(wb[ms] + (size_t)(kc + 2) * 512);
        }
#pragma unroll
        for (int ns = 0; ns < 4; ++ns)
            bfa[ns] = *(const short8*)(atile1 + aoff[ns]);
#pragma unroll
        for (int ms = 0; ms < 4; ++ms)
#pragma unroll
            for (int ns = 0; ns < 4; ++ns)
                acc[ms][ns] = __builtin_amdgcn_mfma_f32_16x16x32_bf16(
                    wfrB[ms], bfa[ns], acc[ms][ns], 0, 0, 0);
    }

    // epilogue: D rows = co (quad*4+rg), cols = px (l15)
#pragma unroll
    for (int ns = 0; ns < 4; ++ns) {
        int p = mt * 128 + pw * 64 + ns * 16 + l15;
        if (p > 360) continue;
#pragma unroll
        for (int ms = 0; ms < 4; ++ms) {
#pragma unroll
            for (int rg = 0; rg < 4; ++rg) {
                int co = (cw * 4 + ms) * 16 + quad * 4 + rg;
                size_t idx = ((size_t)b * TRUNK_C + co) * HW + p;
                out[idx] = acc[ms][ns][rg] + resid[idx];
            }
        }
    }
}

// ------------------------------ kata gpool ----------------------------------
__global__ void gpool_kernel(const bf16* __restrict__ gp, float* __restrict__ pooled) {
    __shared__ float ls[4][64], lm[4][64];
    int b = blockIdx.x;
    int t = threadIdx.x;          // 256
    int c = t & 63, sub = t >> 6;
    float s = 0.0f, mx = -1e30f;
    for (int p = sub; p < HW; p += 4) {
        float v = b2f(gp[((size_t)b * HW + p) * GPOOL_C + c]);
        s += v;
        mx = fmaxf(mx, v);
    }
    ls[sub][c] = s; lm[sub][c] = mx;
    __syncthreads();
    if (t < 64) {
        float ss = ls[0][t] + ls[1][t] + ls[2][t] + ls[3][t];
        float mm = fmaxf(fmaxf(lm[0][t], lm[1][t]), fmaxf(lm[2][t], lm[3][t]));
        float mean = ss * (1.0f / 361.0f);
        pooled[b * 192 + t] = mean;
        pooled[b * 192 + 64 + t] = mean * 0.5f;
        pooled[b * 192 + 128 + t] = mm;
    }
}

// -------------------------- tiny linear (192x192) ---------------------------
__global__ void lin_kernel(const float* __restrict__ pooled, const float* __restrict__ w_lin,
                           float* __restrict__ gpout) {
    int i = blockIdx.x * blockDim.x + threadIdx.x;
    if (i >= BATCH * REG_C) return;
    int b = i / REG_C;
    int oc = i - b * REG_C;
    const float* pr = pooled + b * 192;
    const float* wr = w_lin + oc * 192;
    float s = 0.0f;
    for (int j = 0; j < 192; ++j) s = fmaf(pr[j], wr[j], s);
    gpout[i] = s;
}

// ------------- add gpool bias + bn2 + mish, in-place on reg_pad -------------
__global__ void add_bn2_mish_kernel(bf16* __restrict__ reg_pad, const float* __restrict__ gpout,
                                    const float* __restrict__ bnbuf) {
    const int n = BATCH * HW * REG_C;
    int i = blockIdx.x * blockDim.x + threadIdx.x;
    if (i >= n) return;
    int c = i % REG_C;
    int bp = i / REG_C;
    int p = bp % HW;
    int b = bp / HW;
    int pp = (p / WW + 1) * 21 + (p % WW + 1);
    size_t idx = ((size_t)b * PP + pp) * REG_C + c;
    float v = b2f(reg_pad[idx]) + gpout[b * 192 + c];
    v = v * bnbuf[640 + c] + bnbuf[832 + c];
    reg_pad[idx] = f2b(mish_f(v));
}

// ---------------------------------------------------------------------------
extern "C" void kernel_launch(void* const* d_in, const int* in_sizes, int n_in,
                              void* d_out, int out_size, void* d_ws, size_t ws_size,
                              hipStream_t stream) {
    const float* x     = (const float*)d_in[0];
    const float* bn1_g = (const float*)d_in[1];
    const float* bn1_b = (const float*)d_in[2];
    const float* bn1_m = (const float*)d_in[3];
    const float* bn1_v = (const float*)d_in[4];
    const float* w1a   = (const float*)d_in[5];
    const float* w1b   = (const float*)d_in[6];
    const float* bn1b_g = (const float*)d_in[7];
    const float* bn1b_b = (const float*)d_in[8];
    const float* bn1b_m = (const float*)d_in[9];
    const float* bn1b_v = (const float*)d_in[10];
    const float* w_lin  = (const float*)d_in[11];
    const float* bn2_g  = (const float*)d_in[12];
    const float* bn2_b  = (const float*)d_in[13];
    const float* bn2_m  = (const float*)d_in[14];
    const float* bn2_v  = (const float*)d_in[15];
    const float* w2     = (const float*)d_in[16];
    float* out = (float*)d_out;

    char* ws = (char*)d_ws;
    size_t off = 0;
    auto alloc = [&](size_t bytes) {
        void* p = ws + off;
        off += (bytes + 255) & ~(size_t)255;
        return p;
    };
    bf16*  act_pad = (bf16*)alloc((size_t)BATCH * PP * TRUNK_C * sizeof(bf16));
    bf16*  reg_pad = (bf16*)alloc((size_t)BATCH * PP * REG_C * sizeof(bf16));
    bf16*  gp      = (bf16*)alloc((size_t)BATCH * HW * GPOOL_C * sizeof(bf16));
    bf16*  w1c_p   = (bf16*)alloc((size_t)16 * 72 * 64 * 8 * sizeof(bf16));
    bf16*  w2_p    = (bf16*)alloc((size_t)16 * 54 * 64 * 8 * sizeof(bf16));
    float* pooled  = (float*)alloc((size_t)BATCH * 192 * sizeof(float));
    float* gpout   = (float*)alloc((size_t)BATCH * 192 * sizeof(float));
    float* bnbuf   = (float*)alloc(1024 * sizeof(float));
    (void)ws_size;

    // 1. prep
    hipLaunchKernelGGL(prep_bn_kernel, dim3(1), dim3(512), 0, stream,
                       bn1_g, bn1_b, bn1_m, bn1_v,
                       bn1b_g, bn1b_b, bn1b_m, bn1b_v,
                       bn2_g, bn2_b, bn2_m, bn2_v, bnbuf);
    hipLaunchKernelGGL(prep_w_kernel, dim3(1024), dim3(256), 0, stream,
                       w1a, w1b, w2, w1c_p, w2_p);
    hipLaunchKernelGGL(zero_border_kernel, dim3(BATCH), dim3(256), 0, stream,
                       act_pad, reg_pad);

    // 2. act_pad = mish(bn1(x)), LDS-tiled transpose to channel-last padded
    hipLaunchKernelGGL(bn1_mish_t_kernel, dim3(12, BATCH), dim3(256), 0, stream,
                       x, bnbuf, act_pad);

    // 3. fused conv1: reg_pad raw interior + gp = mish(bn1b(conv))
    hipLaunchKernelGGL(conv1_kernel, dim3(BATCH, 3), dim3(512), 0, stream,
                       act_pad, w1c_p, reg_pad, gp, bnbuf + 512, bnbuf + 576);

    // 4. pooled = kata_gpool(gp); gpout = pooled @ w_lin^T
    hipLaunchKernelGGL(gpool_kernel, dim3(BATCH), dim3(256), 0, stream, gp, pooled);
    hipLaunchKernelGGL(lin_kernel, dim3((BATCH * REG_C + 255) / 256), dim3(256), 0, stream,
                       pooled, w_lin, gpout);

    // 5. reg_pad = mish(bn2(reg_pad + gpout)) in-place (interior only)
    {
        int n = BATCH * HW * REG_C;
        hipLaunchKernelGGL(add_bn2_mish_kernel, dim3((n + 255) / 256), dim3(256), 0, stream,
                           reg_pad, gpout, bnbuf);
    }

    // 6. out = conv(reg_pad, w2) + x, channel-first fp32
    hipLaunchKernelGGL(conv2_kernel, dim3(BATCH, 3), dim3(512), 0, stream,
                       reg_pad, w2_p, x, out);
}